// Round 2
// baseline (690.854 us; speedup 1.0000x reference)
//
#include <hip/hip_runtime.h>
#include <cstdint>
#include <cstddef>

#define E_DIM   1024
#define B_DIM   1024
#define T_STEPS 10
#define OUT_DIM 34
#define OUT_PAD 48
#define LDA     72   // padded LDS row stride (elements) for 64-wide k tiles
#define LDH     40   // padded LDS row stride for h transpose (32 e + pad, 16B-aligned rows)
#define LDP     40   // padded LDS row stride for 32-wide k tiles (projection)

typedef __attribute__((ext_vector_type(4))) float  f32x4;
typedef __attribute__((ext_vector_type(8))) __bf16 bf16x8;

__device__ __forceinline__ unsigned short f2bf(float f) {
    unsigned int u = __float_as_uint(f);
    u = (u + 0x7FFFu + ((u >> 16) & 1u)) >> 16;   // round-to-nearest-even
    return (unsigned short)u;
}
__device__ __forceinline__ float sigmoid_(float x) { return 1.0f / (1.0f + __expf(-x)); }
__device__ __forceinline__ float tanh_(float x)    { return 2.0f / (1.0f + __expf(-2.0f * x)) - 1.0f; }

// Permutation: perm row n = 128*Bn + 64*w + 16*g + j  ->  gate g, e = 32*Bn + 16*w + j.
// Puts all 4 gates of an e-chunk into the 4 n-subtiles of one wave's 64-wide
// n-range, so the LSTM epilogue is lane-local (acc[mt][gate][r]).
__global__ void prep_weights(const float* __restrict__ W_ih, const float* __restrict__ W_hh,
                             const float* __restrict__ b_ih, const float* __restrict__ b_hh,
                             unsigned short* __restrict__ Wsum, unsigned short* __restrict__ Whh,
                             float* __restrict__ bperm) {
    const int n = blockIdx.x;                       // 0..4095 permuted row
    const int g = (n >> 4) & 3;
    const int e = ((n >> 7) << 5) | (((n >> 6) & 1) << 4) | (n & 15);
    const int srow = g * E_DIM + e;
    const size_t src = (size_t)srow * E_DIM;
    const int k = threadIdx.x * 4;
    float4 wi = *(const float4*)(W_ih + src + k);
    float4 wh = *(const float4*)(W_hh + src + k);
    const size_t dst = (size_t)n * E_DIM + k;
    Wsum[dst + 0] = f2bf(wi.x + wh.x);
    Wsum[dst + 1] = f2bf(wi.y + wh.y);
    Wsum[dst + 2] = f2bf(wi.z + wh.z);
    Wsum[dst + 3] = f2bf(wi.w + wh.w);
    Whh[dst + 0] = f2bf(wh.x);
    Whh[dst + 1] = f2bf(wh.y);
    Whh[dst + 2] = f2bf(wh.z);
    Whh[dst + 3] = f2bf(wh.w);
    if (threadIdx.x == 0) bperm[n] = b_ih[srow] + b_hh[srow];
}

// h0 -> bf16 [b][e]; W_out -> bf16 padded to 48 rows
__global__ void prep_state(const float* __restrict__ h0, const float* __restrict__ W_out,
                           unsigned short* __restrict__ hbuf, unsigned short* __restrict__ Woutp) {
    const int b = blockIdx.x;
    const int t = threadIdx.x;
    if (b < 1024) {
        const size_t i = ((size_t)b * 256 + t) * 4;
        float4 hv = *(const float4*)(h0 + i);
        hbuf[i + 0] = f2bf(hv.x);
        hbuf[i + 1] = f2bf(hv.y);
        hbuf[i + 2] = f2bf(hv.z);
        hbuf[i + 3] = f2bf(hv.w);
    } else {
        const int o = b - 1024;                     // 0..47
        const int k = t * 4;
        float4 w = make_float4(0.f, 0.f, 0.f, 0.f);
        if (o < OUT_DIM) w = *(const float4*)(W_out + (size_t)o * E_DIM + k);
        const size_t dst = (size_t)o * E_DIM + k;
        Woutp[dst + 0] = f2bf(w.x);
        Woutp[dst + 1] = f2bf(w.y);
        Woutp[dst + 2] = f2bf(w.z);
        Woutp[dst + 3] = f2bf(w.w);
    }
}

// Permute initial c into the MFMA-accumulator-native flat layout used by lstm_step.
// dst = (((blk*4 + wave)*64 + lane)*8 + mt*4 + r, with blk = bn*16 + bm.
__global__ void prep_c(const float* __restrict__ c0, float* __restrict__ C) {
    const int m = blockIdx.x;
    const int e0 = threadIdx.x * 4;
    float4 v = *(const float4*)(c0 + (size_t)m * E_DIM + e0);
    const int bm = m >> 6, wm = (m >> 5) & 1, mt = (m >> 4) & 1, q = (m >> 2) & 3, r = m & 3;
    const float vv[4] = {v.x, v.y, v.z, v.w};
#pragma unroll
    for (int ii = 0; ii < 4; ++ii) {
        const int e = e0 + ii;
        const int bn = e >> 5, wn = (e >> 4) & 1, j = e & 15;
        const int blk = bn * 16 + bm;
        const int wave = wm * 2 + wn;
        const int lane = q * 16 + j;
        C[(((size_t)blk * 4 + wave) * 64 + lane) * 8 + mt * 4 + r] = vv[ii];
    }
}

// One fused LSTM step: gates = Hin @ Wp^T (+ bperm), then elementwise LSTM.
// Grid (32, 16): bn over 4096 permuted rows (128 each), bm over batch (64 each).
// 256 threads = 4 waves in 2x2 (wm over m:32, wn over n:64); wave tile 32x64 = 2x4 MFMA tiles.
__global__ __launch_bounds__(256, 2) void lstm_step(
    const unsigned short* __restrict__ Wp,   // [4096][1024] bf16 permuted
    const float* __restrict__ bp,            // [4096] permuted bias
    const unsigned short* __restrict__ Hin,  // [1024][1024] bf16
    float* __restrict__ C,                   // [B*E] f32 cell state in MFMA layout
    unsigned short* __restrict__ Hout)       // [1024][1024] bf16
{
    __shared__ __align__(16) unsigned short As[64 * LDA];
    __shared__ __align__(16) unsigned short Bs[128 * LDA];

    const int tid  = threadIdx.x;
    const int wave = tid >> 6;
    const int lane = tid & 63;
    const int bn = blockIdx.x;
    const int bm = blockIdx.y;
    const int wm = wave >> 1;
    const int wn = wave & 1;
    const int j  = lane & 15;
    const int q  = lane >> 4;

    f32x4 acc[2][4];
#pragma unroll
    for (int a = 0; a < 2; ++a)
#pragma unroll
        for (int b = 0; b < 4; ++b) acc[a][b] = (f32x4){0.f, 0.f, 0.f, 0.f};

    const size_t arowbase = (size_t)(bm * 64) * E_DIM;
    const size_t browbase = (size_t)(bn * 128) * E_DIM;

    // staging: A = 64 rows x 8 kslots (2/thread), B = 128 rows x 8 kslots (4/thread)
    uint4 ra[2], rb[4];
#pragma unroll
    for (int i = 0; i < 2; ++i) {
        const int s = i * 256 + tid, row = s >> 3, ks = (s & 7) * 8;
        ra[i] = *(const uint4*)(Hin + arowbase + (size_t)row * E_DIM + ks);
    }
#pragma unroll
    for (int i = 0; i < 4; ++i) {
        const int s = i * 256 + tid, row = s >> 3, ks = (s & 7) * 8;
        rb[i] = *(const uint4*)(Wp + browbase + (size_t)row * E_DIM + ks);
    }

    for (int k0 = 0; k0 < E_DIM; k0 += 64) {
        __syncthreads();
#pragma unroll
        for (int i = 0; i < 2; ++i) {
            const int s = i * 256 + tid, row = s >> 3, ks = (s & 7) * 8;
            *(uint4*)(As + row * LDA + ks) = ra[i];
        }
#pragma unroll
        for (int i = 0; i < 4; ++i) {
            const int s = i * 256 + tid, row = s >> 3, ks = (s & 7) * 8;
            *(uint4*)(Bs + row * LDA + ks) = rb[i];
        }
        __syncthreads();
        if (k0 + 64 < E_DIM) {          // prefetch next tile into registers
#pragma unroll
            for (int i = 0; i < 2; ++i) {
                const int s = i * 256 + tid, row = s >> 3, ks = (s & 7) * 8;
                ra[i] = *(const uint4*)(Hin + arowbase + (size_t)row * E_DIM + (k0 + 64) + ks);
            }
#pragma unroll
            for (int i = 0; i < 4; ++i) {
                const int s = i * 256 + tid, row = s >> 3, ks = (s & 7) * 8;
                rb[i] = *(const uint4*)(Wp + browbase + (size_t)row * E_DIM + (k0 + 64) + ks);
            }
        }
#pragma unroll
        for (int kc = 0; kc < 2; ++kc) {
            bf16x8 av[2], bv[4];
#pragma unroll
            for (int mt = 0; mt < 2; ++mt)
                av[mt] = *(const bf16x8*)(As + (wm * 32 + mt * 16 + j) * LDA + kc * 32 + q * 8);
#pragma unroll
            for (int nt = 0; nt < 4; ++nt)
                bv[nt] = *(const bf16x8*)(Bs + (wn * 64 + nt * 16 + j) * LDA + kc * 32 + q * 8);
#pragma unroll
            for (int mt = 0; mt < 2; ++mt)
#pragma unroll
                for (int nt = 0; nt < 4; ++nt)
                    acc[mt][nt] = __builtin_amdgcn_mfma_f32_16x16x32_bf16(av[mt], bv[nt], acc[mt][nt], 0, 0, 0);
        }
    }

    // ---- Epilogue: nt is the gate index (i,f,g,o); lane-local LSTM update ----
    const int blk = bn * 16 + bm;
    const size_t cbase = (((size_t)blk * 4 + wave) * 64 + lane) * 8;
    float4 cold0 = *(const float4*)(C + cbase);
    float4 cold1 = *(const float4*)(C + cbase + 4);
    const int nb = bn * 128 + wn * 64 + j;
    const float bi = bp[nb +  0];
    const float bf = bp[nb + 16];
    const float bg = bp[nb + 32];
    const float bo = bp[nb + 48];

    __syncthreads();                    // all waves done reading As before reuse
    unsigned short* Hlds = As;          // reuse As as [64][LDH] h-transpose buffer

    float4 cnew[2];
    const float coldv[2][4] = {{cold0.x, cold0.y, cold0.z, cold0.w},
                               {cold1.x, cold1.y, cold1.z, cold1.w}};
#pragma unroll
    for (int mt = 0; mt < 2; ++mt) {
#pragma unroll
        for (int r = 0; r < 4; ++r) {
            const float iv = sigmoid_(acc[mt][0][r] + bi);
            const float fv = sigmoid_(acc[mt][1][r] + bf);
            const float gv = tanh_(acc[mt][2][r] + bg);
            const float ov = sigmoid_(acc[mt][3][r] + bo);
            const float cn = fv * coldv[mt][r] + iv * gv;
            cnew[mt][r] = cn;
            const int rowl = wm * 32 + mt * 16 + q * 4 + r;  // 0..63
            Hlds[rowl * LDH + wn * 16 + j] = f2bf(ov * tanh_(cn));
        }
    }
    *(float4*)(C + cbase)     = cnew[0];
    *(float4*)(C + cbase + 4) = cnew[1];
    __syncthreads();

    // coalesced Hout store: 4 threads per row, 16B each (64B/row contiguous)
    {
        const int row = tid >> 2, kp = (tid & 3) * 8;
        uint4 v = *(const uint4*)(Hlds + row * LDH + kp);
        *(uint4*)(Hout + (size_t)(bm * 64 + row) * E_DIM + bn * 32 + kp) = v;
    }
}

// Output projection: out[b,t,o] = hs[t][b][:] . W_out[o][:] + b_out[o]
// Grid (8, 10): 128 batch rows per block x 48 (padded) outputs. 4 waves x 32 rows.
__global__ __launch_bounds__(256) void proj_kernel(
    const unsigned short* __restrict__ Hs,   // [T][B][E] bf16
    const unsigned short* __restrict__ Wo,   // [48][E] bf16 (rows >=34 zero)
    const float* __restrict__ b_out,         // [34]
    float* __restrict__ Out)                 // [B][T][34]
{
    __shared__ __align__(16) unsigned short As2[128 * LDP];
    __shared__ __align__(16) unsigned short Bs2[OUT_PAD * LDP];

    const int tid = threadIdx.x, wave = tid >> 6, lane = tid & 63;
    const int j = lane & 15, q = lane >> 4;
    const int t  = blockIdx.y;
    const int bb = blockIdx.x;
    const unsigned short* Hbase = Hs + ((size_t)t * B_DIM + (size_t)bb * 128) * E_DIM;

    f32x4 acc[2][3];
#pragma unroll
    for (int a = 0; a < 2; ++a)
#pragma unroll
        for (int b = 0; b < 3; ++b) acc[a][b] = (f32x4){0.f, 0.f, 0.f, 0.f};

    for (int k0 = 0; k0 < E_DIM; k0 += 32) {
        __syncthreads();
#pragma unroll
        for (int i = 0; i < 2; ++i) {
            const int lin = i * 256 + tid;          // 128 rows x 4 slots
            const int row = lin >> 2, ks = lin & 3;
            *(uint4*)(As2 + row * LDP + ks * 8) =
                *(const uint4*)(Hbase + (size_t)row * E_DIM + k0 + ks * 8);
        }
        if (tid < 192) {                            // 48 rows x 4 slots
            const int row = tid >> 2, ks = tid & 3;
            *(uint4*)(Bs2 + row * LDP + ks * 8) =
                *(const uint4*)(Wo + (size_t)row * E_DIM + k0 + ks * 8);
        }
        __syncthreads();
        bf16x8 av[2], bv[3];
#pragma unroll
        for (int mt = 0; mt < 2; ++mt)
            av[mt] = *(const bf16x8*)(As2 + (wave * 32 + mt * 16 + j) * LDP + q * 8);
#pragma unroll
        for (int nt = 0; nt < 3; ++nt)
            bv[nt] = *(const bf16x8*)(Bs2 + (nt * 16 + j) * LDP + q * 8);
#pragma unroll
        for (int mt = 0; mt < 2; ++mt)
#pragma unroll
            for (int nt = 0; nt < 3; ++nt)
                acc[mt][nt] = __builtin_amdgcn_mfma_f32_16x16x32_bf16(av[mt], bv[nt], acc[mt][nt], 0, 0, 0);
    }

#pragma unroll
    for (int nt = 0; nt < 3; ++nt) {
        const int o = nt * 16 + j;
        if (o < OUT_DIM) {
            const float bo = b_out[o];
#pragma unroll
            for (int mt = 0; mt < 2; ++mt)
#pragma unroll
                for (int r = 0; r < 4; ++r) {
                    const int b = bb * 128 + wave * 32 + mt * 16 + q * 4 + r;
                    Out[((size_t)b * T_STEPS + t) * OUT_DIM + o] = acc[mt][nt][r] + bo;
                }
        }
    }
}

extern "C" void kernel_launch(void* const* d_in, const int* in_sizes, int n_in,
                              void* d_out, int out_size, void* d_ws, size_t ws_size,
                              hipStream_t stream) {
    (void)in_sizes; (void)n_in; (void)out_size; (void)ws_size;
    const float* h     = (const float*)d_in[0];
    const float* c     = (const float*)d_in[1];
    const float* W_ih  = (const float*)d_in[2];
    const float* W_hh  = (const float*)d_in[3];
    const float* b_ih  = (const float*)d_in[4];
    const float* b_hh  = (const float*)d_in[5];
    const float* W_out = (const float*)d_in[6];
    const float* b_out = (const float*)d_in[7];
    float* out = (float*)d_out;

    char* ws = (char*)d_ws;
    unsigned short* Wsum  = (unsigned short*)(ws + 0);          //  8 MB
    unsigned short* Whh   = (unsigned short*)(ws + 8388608);    //  8 MB
    float*          bperm = (float*)(ws + 16777216);            // 16 KB
    unsigned short* Woutp = (unsigned short*)(ws + 16793600);   // 96 KB
    float*          cbuf  = (float*)(ws + 16891904);            //  4 MB (MFMA layout)
    unsigned short* h0    = (unsigned short*)(ws + 21086208);   //  2 MB
    unsigned short* hs    = (unsigned short*)(ws + 23183360);   // 20 MB (T x B x E)

    prep_weights<<<4096, 256, 0, stream>>>(W_ih, W_hh, b_ih, b_hh, Wsum, Whh, bperm);
    prep_state<<<1072, 256, 0, stream>>>(h, W_out, h0, Woutp);
    prep_c<<<1024, 256, 0, stream>>>(c, cbuf);

    // step 0: x = 0  ->  W_hh only; steps 1..9: x == h_prev -> fused W_ih + W_hh
    lstm_step<<<dim3(32, 16), 256, 0, stream>>>(Whh, bperm, h0, cbuf, hs);
    for (int t = 1; t < T_STEPS; ++t)
        lstm_step<<<dim3(32, 16), 256, 0, stream>>>(Wsum, bperm,
                                                    hs + (size_t)(t - 1) * B_DIM * E_DIM,
                                                    cbuf,
                                                    hs + (size_t)t * B_DIM * E_DIM);

    proj_kernel<<<dim3(8, T_STEPS), 256, 0, stream>>>(hs, Woutp, b_out, out);
}

// Round 3
// 347.443 us; speedup vs baseline: 1.9884x; 1.9884x over previous
//
#include <hip/hip_runtime.h>
#include <cstdint>
#include <cstddef>

#define E_DIM   1024
#define B_DIM   1024
#define T_STEPS 10
#define OUT_DIM 34
#define OUT_PAD 48
#define LDP     40   // padded LDS row stride for projection kernel
#define HSTR    24   // hbuf row stride (16 cols + pad)

typedef __attribute__((ext_vector_type(4))) float  f32x4;
typedef __attribute__((ext_vector_type(8))) __bf16 bf16x8;

__device__ __forceinline__ unsigned short f2bf(float f) {
    unsigned int u = __float_as_uint(f);
    u = (u + 0x7FFFu + ((u >> 16) & 1u)) >> 16;   // round-to-nearest-even
    return (unsigned short)u;
}
__device__ __forceinline__ float sigmoid_(float x) { return 1.0f / (1.0f + __expf(-x)); }
__device__ __forceinline__ float tanh_(float x)    { return 2.0f / (1.0f + __expf(-2.0f * x)) - 1.0f; }

// Permutation: perm row n = 64*eb + 16*g + j  ->  gate g = (n>>4)&3, e = 16*eb + j.
// Block bn owns perm rows [64bn, 64bn+64) = 4 gates x 16 e-values; gate index == nt tile,
// so the LSTM epilogue is lane-local (acc[mt][gate][r]).
__global__ void prep_weights(const float* __restrict__ W_ih, const float* __restrict__ W_hh,
                             const float* __restrict__ b_ih, const float* __restrict__ b_hh,
                             unsigned short* __restrict__ Wsum, unsigned short* __restrict__ Whh,
                             float* __restrict__ bperm) {
    const int n = blockIdx.x;                       // 0..4095 permuted row
    const int g = (n >> 4) & 3;
    const int e = ((n >> 6) << 4) | (n & 15);
    const int srow = g * E_DIM + e;
    const size_t src = (size_t)srow * E_DIM;
    const int k = threadIdx.x * 4;
    float4 wi = *(const float4*)(W_ih + src + k);
    float4 wh = *(const float4*)(W_hh + src + k);
    const size_t dst = (size_t)n * E_DIM + k;
    Wsum[dst + 0] = f2bf(wi.x + wh.x);
    Wsum[dst + 1] = f2bf(wi.y + wh.y);
    Wsum[dst + 2] = f2bf(wi.z + wh.z);
    Wsum[dst + 3] = f2bf(wi.w + wh.w);
    Whh[dst + 0] = f2bf(wh.x);
    Whh[dst + 1] = f2bf(wh.y);
    Whh[dst + 2] = f2bf(wh.z);
    Whh[dst + 3] = f2bf(wh.w);
    if (threadIdx.x == 0) bperm[n] = b_ih[srow] + b_hh[srow];
}

// h0 -> bf16 [b][e]; W_out -> bf16 padded to 48 rows
__global__ void prep_state(const float* __restrict__ h0, const float* __restrict__ W_out,
                           unsigned short* __restrict__ hbuf, unsigned short* __restrict__ Woutp) {
    const int b = blockIdx.x;
    const int t = threadIdx.x;
    if (b < 1024) {
        const size_t i = ((size_t)b * 256 + t) * 4;
        float4 hv = *(const float4*)(h0 + i);
        hbuf[i + 0] = f2bf(hv.x);
        hbuf[i + 1] = f2bf(hv.y);
        hbuf[i + 2] = f2bf(hv.z);
        hbuf[i + 3] = f2bf(hv.w);
    } else {
        const int o = b - 1024;                     // 0..47
        const int k = t * 4;
        float4 w = make_float4(0.f, 0.f, 0.f, 0.f);
        if (o < OUT_DIM) w = *(const float4*)(W_out + (size_t)o * E_DIM + k);
        const size_t dst = (size_t)o * E_DIM + k;
        Woutp[dst + 0] = f2bf(w.x);
        Woutp[dst + 1] = f2bf(w.y);
        Woutp[dst + 2] = f2bf(w.z);
        Woutp[dst + 3] = f2bf(w.w);
    }
}

// Permute initial c into the MFMA-accumulator-native flat layout used by lstm_step:
// idx = (((bn*4+bm)*8 + wave)*64 + lane)*8 + mt*4 + r
// with m = bm*256 + wave*32 + mt*16 + q*4 + r, e = bn*16 + j, lane = q*16+j.
__global__ void prep_c(const float* __restrict__ c0, float* __restrict__ C) {
    const int m = blockIdx.x;
    const int e0 = threadIdx.x * 4;
    float4 v = *(const float4*)(c0 + (size_t)m * E_DIM + e0);
    const int bm = m >> 8, wave = (m >> 5) & 7, mt = (m >> 4) & 1, q = (m >> 2) & 3, r = m & 3;
    const float vv[4] = {v.x, v.y, v.z, v.w};
#pragma unroll
    for (int ii = 0; ii < 4; ++ii) {
        const int e = e0 + ii;
        const int bn = e >> 4, j = e & 15;
        const int lane = q * 16 + j;
        C[(((size_t)(bn * 4 + bm) * 8 + wave) * 64 + lane) * 8 + mt * 4 + r] = vv[ii];
    }
}

// Fused LSTM step with LDS-resident weight slice and barrier-free K-loop.
// Grid (64, 4): bn over 4096 permuted N-rows (64 each = 16 e), bm over batch (256 each).
// 512 threads = 8 waves; wave owns 32 M-rows (mt=2) x 64 N (nt=4 = the 4 gates).
// Weights staged in two K-halves (64 rows x 512 k = 64 KB), XOR-swizzled chunks.
__global__ __launch_bounds__(512, 2) void lstm_step(
    const unsigned short* __restrict__ Wp,   // [4096][1024] bf16 permuted
    const float* __restrict__ bp,            // [4096] permuted bias
    const unsigned short* __restrict__ Hin,  // [1024][1024] bf16
    float* __restrict__ C,                   // [B*E] f32 cell state in MFMA layout
    unsigned short* __restrict__ Hout)       // [1024][1024] bf16
{
    __shared__ __align__(16) unsigned short smem[32768];   // 64 KB: W half-slice / h transpose

    const int tid  = threadIdx.x;
    const int wave = tid >> 6;
    const int lane = tid & 63;
    const int bn = blockIdx.x;
    const int bm = blockIdx.y;
    const int j  = lane & 15;
    const int q  = lane >> 4;
    const int j7 = j & 7;

    f32x4 acc[2][4];
#pragma unroll
    for (int a = 0; a < 2; ++a)
#pragma unroll
        for (int b = 0; b < 4; ++b) acc[a][b] = (f32x4){0.f, 0.f, 0.f, 0.f};

    // hoisted far-from-use loads: biases + old cell state
    const int nb = bn * 64 + j;
    const float bi = bp[nb +  0];
    const float bf = bp[nb + 16];
    const float bg = bp[nb + 32];
    const float bo = bp[nb + 48];
    const size_t cbase = (((size_t)(bn * 4 + bm) * 8 + wave) * 64 + lane) * 8;
    float4 cold0 = *(const float4*)(C + cbase);
    float4 cold1 = *(const float4*)(C + cbase + 4);

    // A row base (per mt): m = bm*256 + wave*32 + mt*16 + j
    const unsigned short* arow0 = Hin + (size_t)(bm * 256 + wave * 32 + j) * E_DIM + q * 8;
    const unsigned short* arow1 = arow0 + (size_t)16 * E_DIM;
    const unsigned short* wrow  = Wp + (size_t)(bn * 64) * E_DIM;

#pragma unroll
    for (int half = 0; half < 2; ++half) {
        const int kh = half * 512;

        // prefetch first 4 A k-steps of this half (overlaps the W staging below)
        uint4 ra[4][2];
#pragma unroll
        for (int p = 0; p < 4; ++p) {
            ra[p][0] = *(const uint4*)(arow0 + kh + p * 32);
            ra[p][1] = *(const uint4*)(arow1 + kh + p * 32);
        }

        __syncthreads();                    // previous half's reads done before overwrite
        // stage W half-slice: 64 rows x 64 chunks(8 elem), chunk c stored at c^(row&7)
#pragma unroll
        for (int i = 0; i < 8; ++i) {
            const int s = i * 512 + tid;
            const int row = s >> 6, c = s & 63;
            uint4 w = *(const uint4*)(wrow + (size_t)row * E_DIM + kh + c * 8);
            *(uint4*)(smem + row * 512 + ((c ^ (row & 7)) << 3)) = w;
        }
        __syncthreads();

#pragma unroll
        for (int ks = 0; ks < 16; ++ks) {
            bf16x8 av0 = __builtin_bit_cast(bf16x8, ra[ks & 3][0]);
            bf16x8 av1 = __builtin_bit_cast(bf16x8, ra[ks & 3][1]);
            const int coff = ((ks * 4 + q) ^ j7) << 3;   // same for all nt (row&7 == j&7)
            bf16x8 bv[4];
#pragma unroll
            for (int nt = 0; nt < 4; ++nt)
                bv[nt] = *(const bf16x8*)(smem + (nt * 16 + j) * 512 + coff);
#pragma unroll
            for (int nt = 0; nt < 4; ++nt) {
                acc[0][nt] = __builtin_amdgcn_mfma_f32_16x16x32_bf16(av0, bv[nt], acc[0][nt], 0, 0, 0);
                acc[1][nt] = __builtin_amdgcn_mfma_f32_16x16x32_bf16(av1, bv[nt], acc[1][nt], 0, 0, 0);
            }
            if (ks < 12) {                  // keep the 4-deep A pipeline full
                ra[ks & 3][0] = *(const uint4*)(arow0 + kh + (ks + 4) * 32);
                ra[ks & 3][1] = *(const uint4*)(arow1 + kh + (ks + 4) * 32);
            }
        }
    }

    // ---- Epilogue: nt is the gate index (i,f,g,o); lane-local LSTM update ----
    __syncthreads();                        // all waves done reading W before aliasing smem
    float4 cnew[2];
    const float coldv[2][4] = {{cold0.x, cold0.y, cold0.z, cold0.w},
                               {cold1.x, cold1.y, cold1.z, cold1.w}};
#pragma unroll
    for (int mt = 0; mt < 2; ++mt) {
#pragma unroll
        for (int r = 0; r < 4; ++r) {
            const float iv = sigmoid_(acc[mt][0][r] + bi);
            const float fv = sigmoid_(acc[mt][1][r] + bf);
            const float gv = tanh_(acc[mt][2][r] + bg);
            const float ov = sigmoid_(acc[mt][3][r] + bo);
            const float cn = fv * coldv[mt][r] + iv * gv;
            cnew[mt][r] = cn;
            const int rowl = wave * 32 + mt * 16 + q * 4 + r;   // 0..255
            smem[rowl * HSTR + j] = f2bf(ov * tanh_(cn));
        }
    }
    *(float4*)(C + cbase)     = cnew[0];
    *(float4*)(C + cbase + 4) = cnew[1];
    __syncthreads();

    // coalesced Hout store: 2 threads per row, 16B each (32B/row)
    {
        const int row = tid >> 1, part = tid & 1;
        uint4 v = *(const uint4*)(smem + row * HSTR + part * 8);
        *(uint4*)(Hout + (size_t)(bm * 256 + row) * E_DIM + bn * 16 + part * 8) = v;
    }
}

// Output projection: out[b,t,o] = hs[t][b][:] . W_out[o][:] + b_out[o]
// Grid (8, 10): 128 batch rows per block x 48 (padded) outputs. 4 waves x 32 rows.
__global__ __launch_bounds__(256) void proj_kernel(
    const unsigned short* __restrict__ Hs,   // [T][B][E] bf16
    const unsigned short* __restrict__ Wo,   // [48][E] bf16 (rows >=34 zero)
    const float* __restrict__ b_out,         // [34]
    float* __restrict__ Out)                 // [B][T][34]
{
    __shared__ __align__(16) unsigned short As2[128 * LDP];
    __shared__ __align__(16) unsigned short Bs2[OUT_PAD * LDP];

    const int tid = threadIdx.x, wave = tid >> 6, lane = tid & 63;
    const int j = lane & 15, q = lane >> 4;
    const int t  = blockIdx.y;
    const int bb = blockIdx.x;
    const unsigned short* Hbase = Hs + ((size_t)t * B_DIM + (size_t)bb * 128) * E_DIM;

    f32x4 acc[2][3];
#pragma unroll
    for (int a = 0; a < 2; ++a)
#pragma unroll
        for (int b = 0; b < 3; ++b) acc[a][b] = (f32x4){0.f, 0.f, 0.f, 0.f};

    for (int k0 = 0; k0 < E_DIM; k0 += 32) {
        __syncthreads();
#pragma unroll
        for (int i = 0; i < 2; ++i) {
            const int lin = i * 256 + tid;          // 128 rows x 4 slots
            const int row = lin >> 2, ks = lin & 3;
            *(uint4*)(As2 + row * LDP + ks * 8) =
                *(const uint4*)(Hbase + (size_t)row * E_DIM + k0 + ks * 8);
        }
        if (tid < 192) {                            // 48 rows x 4 slots
            const int row = tid >> 2, ks = tid & 3;
            *(uint4*)(Bs2 + row * LDP + ks * 8) =
                *(const uint4*)(Wo + (size_t)row * E_DIM + k0 + ks * 8);
        }
        __syncthreads();
        bf16x8 av[2], bv[3];
#pragma unroll
        for (int mt = 0; mt < 2; ++mt)
            av[mt] = *(const bf16x8*)(As2 + (wave * 32 + mt * 16 + j) * LDP + q * 8);
#pragma unroll
        for (int nt = 0; nt < 3; ++nt)
            bv[nt] = *(const bf16x8*)(Bs2 + (nt * 16 + j) * LDP + q * 8);
#pragma unroll
        for (int mt = 0; mt < 2; ++mt)
#pragma unroll
            for (int nt = 0; nt < 3; ++nt)
                acc[mt][nt] = __builtin_amdgcn_mfma_f32_16x16x32_bf16(av[mt], bv[nt], acc[mt][nt], 0, 0, 0);
    }

#pragma unroll
    for (int nt = 0; nt < 3; ++nt) {
        const int o = nt * 16 + j;
        if (o < OUT_DIM) {
            const float bo = b_out[o];
#pragma unroll
            for (int mt = 0; mt < 2; ++mt)
#pragma unroll
                for (int r = 0; r < 4; ++r) {
                    const int b = bb * 128 + wave * 32 + mt * 16 + q * 4 + r;
                    Out[((size_t)b * T_STEPS + t) * OUT_DIM + o] = acc[mt][nt][r] + bo;
                }
        }
    }
}

extern "C" void kernel_launch(void* const* d_in, const int* in_sizes, int n_in,
                              void* d_out, int out_size, void* d_ws, size_t ws_size,
                              hipStream_t stream) {
    (void)in_sizes; (void)n_in; (void)out_size; (void)ws_size;
    const float* h     = (const float*)d_in[0];
    const float* c     = (const float*)d_in[1];
    const float* W_ih  = (const float*)d_in[2];
    const float* W_hh  = (const float*)d_in[3];
    const float* b_ih  = (const float*)d_in[4];
    const float* b_hh  = (const float*)d_in[5];
    const float* W_out = (const float*)d_in[6];
    const float* b_out = (const float*)d_in[7];
    float* out = (float*)d_out;

    char* ws = (char*)d_ws;
    unsigned short* Wsum  = (unsigned short*)(ws + 0);          //  8 MB
    unsigned short* Whh   = (unsigned short*)(ws + 8388608);    //  8 MB
    float*          bperm = (float*)(ws + 16777216);            // 16 KB
    unsigned short* Woutp = (unsigned short*)(ws + 16793600);   // 96 KB
    float*          cbuf  = (float*)(ws + 16891904);            //  4 MB (MFMA layout)
    unsigned short* h0    = (unsigned short*)(ws + 21086208);   //  2 MB
    unsigned short* hs    = (unsigned short*)(ws + 23183360);   // 20 MB (T x B x E)

    prep_weights<<<4096, 256, 0, stream>>>(W_ih, W_hh, b_ih, b_hh, Wsum, Whh, bperm);
    prep_state<<<1072, 256, 0, stream>>>(h, W_out, h0, Woutp);
    prep_c<<<1024, 256, 0, stream>>>(c, cbuf);

    // step 0: x = 0  ->  W_hh only; steps 1..9: x == h_prev -> fused W_ih + W_hh
    lstm_step<<<dim3(64, 4), 512, 0, stream>>>(Whh, bperm, h0, cbuf, hs);
    for (int t = 1; t < T_STEPS; ++t)
        lstm_step<<<dim3(64, 4), 512, 0, stream>>>(Wsum, bperm,
                                                   hs + (size_t)(t - 1) * B_DIM * E_DIM,
                                                   cbuf,
                                                   hs + (size_t)t * B_DIM * E_DIM);

    proj_kernel<<<dim3(8, T_STEPS), 256, 0, stream>>>(hs, Woutp, b_out, out);
}